// Round 10
// baseline (547.765 us; speedup 1.0000x reference)
//
#include <hip/hip_runtime.h>
#include <hip/hip_bf16.h>
#include <hip/hip_fp16.h>

// ---------------- problem constants (match reference) ----------------
constexpr int N_NODES  = 50000;
constexpr int N_EDGES  = 800000;
constexpr int NE_TOT   = N_EDGES + N_NODES;   // edges + self loops
constexpr int COL_MAX  = NE_TOT + 7 * N_NODES; // worst-case padded CSR records
constexpr int F_HID    = 128;
constexpr int N_GRAPHS = 64;
constexpr float BN_EPS = 1e-5f;
constexpr int NB_SCAN  = (N_NODES + 1023) / 1024;   // 49

using short8  = __attribute__((ext_vector_type(8))) short;
using float4v = __attribute__((ext_vector_type(4))) float;

__device__ __forceinline__ ushort f2bf(float f) {
    uint u = __float_as_uint(f);
    return (ushort)((u + 0x7fffu + ((u >> 16) & 1u)) >> 16);   // RNE
}
__device__ __forceinline__ float bflo(uint u) { return __uint_as_float(u << 16); }
__device__ __forceinline__ float bfhi(uint u) { return __uint_as_float(u & 0xffff0000u); }
__device__ __forceinline__ float bfround(float f) { return __uint_as_float(((uint)f2bf(f)) << 16); }

// ---------------- merged prep: conv_w(all 3) | degree count ----------------
constexpr int CONVW_ELEMS  = 96 * 128 + 2 * 128 * 128;                 // 45056
constexpr int CONVW_BLOCKS = (CONVW_ELEMS + 255) / 256;                // 176
constexpr int COUNT_BLOCKS = (N_EDGES + 255) / 256;                    // 3125
constexpr int PREP_BLOCKS  = CONVW_BLOCKS + COUNT_BLOCKS;

__global__ __launch_bounds__(256) void prep_kernel(const int* __restrict__ ei,
                                                   const float* __restrict__ W1, const float* __restrict__ W2,
                                                   const float* __restrict__ W3,
                                                   ushort* __restrict__ W1t, ushort* __restrict__ W2t,
                                                   ushort* __restrict__ W3t, int* __restrict__ cnt) {
    int b = blockIdx.x;
    if (b < CONVW_BLOCKS) {
        int i = b * 256 + threadIdx.x;
        constexpr int S1 = 96 * 128, S2 = S1 + 128 * 128, S3 = S2 + 128 * 128;
        if (i < S1) {
            int n = i & 127, k = i >> 7;
            W1t[n * 96 + k] = f2bf(W1[i]);
        } else if (i < S2) {
            int j = i - S1, n = j & 127, k = j >> 7;
            W2t[n * 128 + k] = f2bf(W2[j]);
        } else if (i < S3) {
            int j = i - S2, n = j & 127, k = j >> 7;
            W3t[n * 128 + k] = f2bf(W3[j]);
        }
    } else {
        int i = (b - CONVW_BLOCKS) * 256 + threadIdx.x;
        if (i < N_EDGES) atomicAdd(&cnt[ei[N_EDGES + i]], 1);   // dst in-degree (cnt pre-zeroed)
    }
}

// ---------------- scan phase 1: block-local exclusive scan over padded row lengths ----------------
// row length = pad8(cnt[i] + 1)   (+1 self loop, padded to multiple of 8)
__global__ __launch_bounds__(1024) void scan_blocks_kernel(const int* __restrict__ cnt,
                                                           int* __restrict__ row_ptr,
                                                           int* __restrict__ blockSums) {
    int tid = threadIdx.x;
    int gid = blockIdx.x * 1024 + tid;
    int v = (gid < N_NODES) ? ((cnt[gid] + 8) & ~7) : 0;
    int lane = tid & 63, wid = tid >> 6;
    int x = v;
#pragma unroll
    for (int off = 1; off < 64; off <<= 1) {
        int y = __shfl_up(x, off);
        if (lane >= off) x += y;
    }
    __shared__ int wsum[16];
    if (lane == 63) wsum[wid] = x;
    __syncthreads();
    if (tid < 16) {
        int w = wsum[tid];
        int xx = w;
#pragma unroll
        for (int off = 1; off < 16; off <<= 1) {
            int y = __shfl_up(xx, off);
            if (tid >= off) xx += y;
        }
        wsum[tid] = xx - w;
    }
    __syncthreads();
    int incl = x + wsum[wid];
    if (gid < N_NODES) row_ptr[gid] = incl - v;
    if (tid == 1023) blockSums[blockIdx.x] = incl;
}

// ---------------- scan phase 2 (merged totals+finalize): every block re-scans the 49 block sums ----------------
__global__ __launch_bounds__(256) void finalize_kernel(int* __restrict__ row_ptr, const int* __restrict__ blockSums,
                                                       const int* __restrict__ cnt, float* __restrict__ dinv,
                                                       int* __restrict__ cursor) {
    __shared__ int boff[64];
    if (threadIdx.x < 64) {   // one wave: exclusive prefix over blockSums
        int v = (threadIdx.x < NB_SCAN) ? blockSums[threadIdx.x] : 0;
        int x = v;
#pragma unroll
        for (int off = 1; off < 64; off <<= 1) {
            int y = __shfl_up(x, off);
            if ((int)threadIdx.x >= off) x += y;
        }
        boff[threadIdx.x] = x - v;
        if (threadIdx.x == NB_SCAN - 1 && blockIdx.x == 0) row_ptr[N_NODES] = x;   // total
    }
    __syncthreads();
    int i = blockIdx.x * 256 + threadIdx.x;
    if (i >= N_NODES) return;
    int rp = row_ptr[i] + boff[i >> 10];
    row_ptr[i] = rp;
    cursor[i] = rp;
    dinv[i] = rsqrtf((float)(cnt[i] + 1));   // degree incl self loop
}

// ---------------- merged fill | layer-1 MFMA GEMM (f32 A, in-register bf16 convert) ----------------
constexpr int GEMM1_BLOCKS = (N_NODES + 63) / 64;       // 782
constexpr int FILL_BLOCKS  = (NE_TOT + 255) / 256;      // 3321

__global__ __launch_bounds__(256) void fillgemm_kernel(const int* __restrict__ ei, const float* __restrict__ dinv,
                                                       int* __restrict__ cursor, uint* __restrict__ col,
                                                       const float* __restrict__ X, const ushort* __restrict__ Wt,
                                                       ushort* __restrict__ C) {
    if (blockIdx.x < GEMM1_BLOCKS) {
        // ---- layer-1 GEMM: C[N,128] = bf16(X[N,96]) @ W ----
        constexpr int K = 96, KSTEPS = 3;
        int wave = threadIdx.x >> 6, lane = threadIdx.x & 63;
        int m = lane & 15, quad = lane >> 4;
        int row_base = blockIdx.x * 64 + wave * 16;
        short8 afrag[KSTEPS];
        int arow = min(row_base + m, N_NODES - 1);
#pragma unroll
        for (int ks = 0; ks < KSTEPS; ks++) {
            const float* src = X + (size_t)arow * K + ks * 32 + quad * 8;
            float4 a0 = *(const float4*)src;
            float4 a1 = *(const float4*)(src + 4);
            afrag[ks][0] = (short)f2bf(a0.x); afrag[ks][1] = (short)f2bf(a0.y);
            afrag[ks][2] = (short)f2bf(a0.z); afrag[ks][3] = (short)f2bf(a0.w);
            afrag[ks][4] = (short)f2bf(a1.x); afrag[ks][5] = (short)f2bf(a1.y);
            afrag[ks][6] = (short)f2bf(a1.z); afrag[ks][7] = (short)f2bf(a1.w);
        }
#pragma unroll
        for (int nt = 0; nt < 8; nt++) {
            float4v acc = {0.f, 0.f, 0.f, 0.f};
            const ushort* wbase = Wt + (size_t)(nt * 16 + m) * K + quad * 8;
#pragma unroll
            for (int ks = 0; ks < KSTEPS; ks++) {
                short8 bfrag = *(const short8*)(wbase + ks * 32);
                acc = __builtin_amdgcn_mfma_f32_16x16x32_bf16(afrag[ks], bfrag, acc, 0, 0, 0);
            }
            int colg = nt * 16 + m;
#pragma unroll
            for (int r = 0; r < 4; r++) {
                int rowg = row_base + quad * 4 + r;
                if (rowg < N_NODES) C[(size_t)rowg * F_HID + colg] = f2bf(acc[r]);
            }
        }
    } else {
        // ---- CSR fill: packed record (fp16 norm | u16 src), plain 4B scattered store ----
        // (R8 tried atomicExch here: WRITE fell 76->65MB but atomic throughput
        //  serialized the kernel 46->72us. Plain store is the better tradeoff.)
        int i = (blockIdx.x - GEMM1_BLOCKS) * 256 + threadIdx.x;
        if (i >= NE_TOT) return;
        int s, d;
        if (i < N_EDGES) { s = ei[i]; d = ei[N_EDGES + i]; }
        else             { s = i - N_EDGES; d = s; }
        int pos = atomicAdd(&cursor[d], 1);
        float nrm = dinv[s] * dinv[d];
        uint h16 = (uint)__half_as_ushort(__float2half(nrm));
        col[pos] = (h16 << 16) | (uint)s;
    }
}

// ---------------- MFMA transform with fused BN+ReLU on A (layers 2,3), bf16 in/out ----------------
__global__ __launch_bounds__(256) void mfma_gemm_bn_kernel(const ushort* __restrict__ A, const float* __restrict__ cs,
                                                           const float* __restrict__ gam, const float* __restrict__ bet,
                                                           const ushort* __restrict__ Wt, ushort* __restrict__ C) {
    constexpr int K = 128, KSTEPS = 4;
    int wave = threadIdx.x >> 6, lane = threadIdx.x & 63;
    int m = lane & 15, quad = lane >> 4;
    int row_base = blockIdx.x * 64 + wave * 16;
    int arow = min(row_base + m, N_NODES - 1);
    constexpr float invN = 1.0f / N_NODES;

    short8 afrag[KSTEPS];
#pragma unroll
    for (int ks = 0; ks < KSTEPS; ks++) {
        int k0 = ks * 32 + quad * 8;
        uint4 av = *(const uint4*)(A + (size_t)arow * K + k0);   // 8 bf16
        float vals[8] = {bflo(av.x), bfhi(av.x), bflo(av.y), bfhi(av.y),
                         bflo(av.z), bfhi(av.z), bflo(av.w), bfhi(av.w)};
#pragma unroll
        for (int jj = 0; jj < 8; jj += 4) {
            float4 sv = *(const float4*)(cs + k0 + jj);
            float4 qv = *(const float4*)(cs + 128 + k0 + jj);
            float4 gv = *(const float4*)(gam + k0 + jj);
            float4 bv = *(const float4*)(bet + k0 + jj);
            const float* s = (const float*)&sv; const float* q = (const float*)&qv;
            const float* g = (const float*)&gv; const float* b = (const float*)&bv;
#pragma unroll
            for (int t = 0; t < 4; t++) {
                float mean = s[t] * invN;
                float var  = q[t] * invN - mean * mean;
                float sc   = g[t] * rsqrtf(var + BN_EPS);
                float val  = fmaxf((vals[jj + t] - mean) * sc + b[t], 0.0f);
                afrag[ks][jj + t] = (short)f2bf(val);
            }
        }
    }

#pragma unroll
    for (int nt = 0; nt < 8; nt++) {
        float4v acc = {0.f, 0.f, 0.f, 0.f};
        const ushort* wbase = Wt + (size_t)(nt * 16 + m) * K + quad * 8;
#pragma unroll
        for (int ks = 0; ks < KSTEPS; ks++) {
            short8 bfrag = *(const short8*)(wbase + ks * 32);
            acc = __builtin_amdgcn_mfma_f32_16x16x32_bf16(afrag[ks], bfrag, acc, 0, 0, 0);
        }
        int colg = nt * 16 + m;
#pragma unroll
        for (int r = 0; r < 4; r++) {
            int rowg = row_base + quad * 4 + r;
            if (rowg < N_NODES) C[(size_t)rowg * F_HID + colg] = f2bf(acc[r]);
        }
    }
}

// ---------------- sparse aggregation + fused BN stats ----------------
// 1024 threads = 16 waves = 16 rows per block; grid = N/16 = 3125 exact.
// each quarter (16 lanes) serves one edge; lane covers cols sl*8..sl*8+7 (uint4 = 8 bf16)
// rows padded to x8 with zero records (src=0, w=0). bf16 out.
// Column sum/sumsq of the ROUNDED outputs accumulate in LDS, flushed once per block.
__global__ __launch_bounds__(1024) void aggregate_stats_kernel(const ushort* __restrict__ h,
                                                               const int* __restrict__ row_ptr,
                                                               const uint* __restrict__ col,
                                                               ushort* __restrict__ outp,
                                                               float* __restrict__ colstats) {
    __shared__ float ssum[F_HID], ssq[F_HID];
    if (threadIdx.x < F_HID) { ssum[threadIdx.x] = 0.f; ssq[threadIdx.x] = 0.f; }
    __syncthreads();

    int wave = threadIdx.x >> 6;
    int lane = threadIdx.x & 63;
    int wv   = blockIdx.x * 16 + wave;   // always < N_NODES (grid exact)
    int q  = lane >> 4;     // 0..3 edge slot
    int sl = lane & 15;     // col group
    int beg = row_ptr[wv], end = row_ptr[wv + 1];
    float a0 = 0, a1 = 0, a2 = 0, a3 = 0, a4 = 0, a5 = 0, a6 = 0, a7 = 0;
    int base = beg;
    for (; base + 16 <= end; base += 16) {   // 16 edges per iteration, 4 gathers in flight per lane
        uint r0 = col[base + q];
        uint r1 = col[base + 4 + q];
        uint r2 = col[base + 8 + q];
        uint r3 = col[base + 12 + q];
        uint4 v0 = *(const uint4*)(h + (size_t)(r0 & 0xFFFFu) * F_HID + sl * 8);
        uint4 v1 = *(const uint4*)(h + (size_t)(r1 & 0xFFFFu) * F_HID + sl * 8);
        uint4 v2 = *(const uint4*)(h + (size_t)(r2 & 0xFFFFu) * F_HID + sl * 8);
        uint4 v3 = *(const uint4*)(h + (size_t)(r3 & 0xFFFFu) * F_HID + sl * 8);
        float w0 = __half2float(__ushort_as_half((ushort)(r0 >> 16)));
        float w1 = __half2float(__ushort_as_half((ushort)(r1 >> 16)));
        float w2 = __half2float(__ushort_as_half((ushort)(r2 >> 16)));
        float w3 = __half2float(__ushort_as_half((ushort)(r3 >> 16)));
        a0 += w0 * bflo(v0.x); a1 += w0 * bfhi(v0.x); a2 += w0 * bflo(v0.y); a3 += w0 * bfhi(v0.y);
        a4 += w0 * bflo(v0.z); a5 += w0 * bfhi(v0.z); a6 += w0 * bflo(v0.w); a7 += w0 * bfhi(v0.w);
        a0 += w1 * bflo(v1.x); a1 += w1 * bfhi(v1.x); a2 += w1 * bflo(v1.y); a3 += w1 * bfhi(v1.y);
        a4 += w1 * bflo(v1.z); a5 += w1 * bfhi(v1.z); a6 += w1 * bflo(v1.w); a7 += w1 * bfhi(v1.w);
        a0 += w2 * bflo(v2.x); a1 += w2 * bfhi(v2.x); a2 += w2 * bflo(v2.y); a3 += w2 * bfhi(v2.y);
        a4 += w2 * bflo(v2.z); a5 += w2 * bfhi(v2.z); a6 += w2 * bflo(v2.w); a7 += w2 * bfhi(v2.w);
        a0 += w3 * bflo(v3.x); a1 += w3 * bfhi(v3.x); a2 += w3 * bflo(v3.y); a3 += w3 * bfhi(v3.y);
        a4 += w3 * bflo(v3.z); a5 += w3 * bfhi(v3.z); a6 += w3 * bflo(v3.w); a7 += w3 * bfhi(v3.w);
    }
    if (base < end) {   // exactly 8 remain (row length % 8 == 0)
        uint r0 = col[base + q];
        uint r1 = col[base + 4 + q];
        uint4 v0 = *(const uint4*)(h + (size_t)(r0 & 0xFFFFu) * F_HID + sl * 8);
        uint4 v1 = *(const uint4*)(h + (size_t)(r1 & 0xFFFFu) * F_HID + sl * 8);
        float w0 = __half2float(__ushort_as_half((ushort)(r0 >> 16)));
        float w1 = __half2float(__ushort_as_half((ushort)(r1 >> 16)));
        a0 += w0 * bflo(v0.x); a1 += w0 * bfhi(v0.x); a2 += w0 * bflo(v0.y); a3 += w0 * bfhi(v0.y);
        a4 += w0 * bflo(v0.z); a5 += w0 * bfhi(v0.z); a6 += w0 * bflo(v0.w); a7 += w0 * bfhi(v0.w);
        a0 += w1 * bflo(v1.x); a1 += w1 * bfhi(v1.x); a2 += w1 * bflo(v1.y); a3 += w1 * bfhi(v1.y);
        a4 += w1 * bflo(v1.z); a5 += w1 * bfhi(v1.z); a6 += w1 * bflo(v1.w); a7 += w1 * bfhi(v1.w);
    }
    // combine quarters: +16 then +32
    a0 += __shfl_down(a0, 16); a1 += __shfl_down(a1, 16); a2 += __shfl_down(a2, 16); a3 += __shfl_down(a3, 16);
    a4 += __shfl_down(a4, 16); a5 += __shfl_down(a5, 16); a6 += __shfl_down(a6, 16); a7 += __shfl_down(a7, 16);
    a0 += __shfl_down(a0, 32); a1 += __shfl_down(a1, 32); a2 += __shfl_down(a2, 32); a3 += __shfl_down(a3, 32);
    a4 += __shfl_down(a4, 32); a5 += __shfl_down(a5, 32); a6 += __shfl_down(a6, 32); a7 += __shfl_down(a7, 32);
    if (q == 0) {
        // round once; store the rounded values and accumulate stats of the SAME values
        float r0 = bfround(a0), r1 = bfround(a1), r2 = bfround(a2), r3 = bfround(a3);
        float r4 = bfround(a4), r5 = bfround(a5), r6 = bfround(a6), r7 = bfround(a7);
        uint4 o;
        o.x = (uint)f2bf(r0) | ((uint)f2bf(r1) << 16);
        o.y = (uint)f2bf(r2) | ((uint)f2bf(r3) << 16);
        o.z = (uint)f2bf(r4) | ((uint)f2bf(r5) << 16);
        o.w = (uint)f2bf(r6) | ((uint)f2bf(r7) << 16);
        *(uint4*)(outp + (size_t)wv * F_HID + sl * 8) = o;
        int c0 = sl * 8;
        atomicAdd(&ssum[c0 + 0], r0); atomicAdd(&ssq[c0 + 0], r0 * r0);
        atomicAdd(&ssum[c0 + 1], r1); atomicAdd(&ssq[c0 + 1], r1 * r1);
        atomicAdd(&ssum[c0 + 2], r2); atomicAdd(&ssq[c0 + 2], r2 * r2);
        atomicAdd(&ssum[c0 + 3], r3); atomicAdd(&ssq[c0 + 3], r3 * r3);
        atomicAdd(&ssum[c0 + 4], r4); atomicAdd(&ssq[c0 + 4], r4 * r4);
        atomicAdd(&ssum[c0 + 5], r5); atomicAdd(&ssq[c0 + 5], r5 * r5);
        atomicAdd(&ssum[c0 + 6], r6); atomicAdd(&ssq[c0 + 6], r6 * r6);
        atomicAdd(&ssum[c0 + 7], r7); atomicAdd(&ssq[c0 + 7], r7 * r7);
    }
    __syncthreads();
    if (threadIdx.x < F_HID) {
        atomicAdd(&colstats[threadIdx.x],         ssum[threadIdx.x]);
        atomicAdd(&colstats[F_HID + threadIdx.x], ssq[threadIdx.x]);
    }
}

// ---------------- fused layer-3 BN+ReLU + graph pooling (bf16 in) ----------------
constexpr int POOL_ROWS = 128;
__global__ __launch_bounds__(256) void pool_bn_kernel(const ushort* __restrict__ h, const float* __restrict__ cs,
                                                      const float* __restrict__ gam, const float* __restrict__ bet,
                                                      const int* __restrict__ batch, float* __restrict__ pooled_sum) {
    int row0 = blockIdx.x * POOL_ROWS;
    int c4 = (threadIdx.x & 31) * 4;
    int stripe = threadIdx.x >> 5;   // 0..7
    __shared__ int sbatch[POOL_ROWS];
    if (threadIdx.x < POOL_ROWS) {
        int r = row0 + threadIdx.x;
        sbatch[threadIdx.x] = (r < N_NODES) ? batch[r] : -1;
    }
    __syncthreads();
    int nrows = min(POOL_ROWS, N_NODES - row0);
    if (stripe >= nrows) return;
    constexpr float invN = 1.0f / N_NODES;
    float mean[4], scl[4], bb[4];
#pragma unroll
    for (int t = 0; t < 4; t++) {
        float mn = cs[c4 + t] * invN;
        float var = cs[128 + c4 + t] * invN - mn * mn;
        mean[t] = mn;
        scl[t] = gam[c4 + t] * rsqrtf(var + BN_EPS);
        bb[t] = bet[c4 + t];
    }
    int cur = sbatch[stripe];
    float a0 = 0, a1 = 0, a2 = 0, a3 = 0;
    for (int r = stripe; r < nrows; r += 8) {
        int g = sbatch[r];
        if (g != cur) {
            atomicAdd(&pooled_sum[cur * F_HID + c4 + 0], a0);
            atomicAdd(&pooled_sum[cur * F_HID + c4 + 1], a1);
            atomicAdd(&pooled_sum[cur * F_HID + c4 + 2], a2);
            atomicAdd(&pooled_sum[cur * F_HID + c4 + 3], a3);
            cur = g; a0 = a1 = a2 = a3 = 0.f;
        }
        uint2 v = *(const uint2*)(h + (size_t)(row0 + r) * F_HID + c4);
        a0 += fmaxf((bflo(v.x) - mean[0]) * scl[0] + bb[0], 0.f);
        a1 += fmaxf((bfhi(v.x) - mean[1]) * scl[1] + bb[1], 0.f);
        a2 += fmaxf((bflo(v.y) - mean[2]) * scl[2] + bb[2], 0.f);
        a3 += fmaxf((bfhi(v.y) - mean[3]) * scl[3] + bb[3], 0.f);
    }
    atomicAdd(&pooled_sum[cur * F_HID + c4 + 0], a0);
    atomicAdd(&pooled_sum[cur * F_HID + c4 + 1], a1);
    atomicAdd(&pooled_sum[cur * F_HID + c4 + 2], a2);
    atomicAdd(&pooled_sum[cur * F_HID + c4 + 3], a3);
}

// ---------------- MLP head (boundary search + divide-by-count folded in) ----------------
__global__ __launch_bounds__(256) void mlp_kernel(const float* __restrict__ pooled_sum, const int* __restrict__ batch,
                                                  const float* __restrict__ Wf1, const float* __restrict__ bf1,
                                                  const float* __restrict__ Wf2, const float* __restrict__ bf2,
                                                  float* __restrict__ out) {
    __shared__ float p[128];
    __shared__ float h1[256];
    __shared__ int se[2];
    int g = blockIdx.x, t = threadIdx.x;
    if (t < 2) {   // lower_bound(batch, g + t)
        int target = g + t;
        int lo = 0, hi = N_NODES;
        while (lo < hi) {
            int mid = (lo + hi) >> 1;
            if (batch[mid] < target) lo = mid + 1; else hi = mid;
        }
        se[t] = lo;
    }
    __syncthreads();
    if (t < 128) {
        float cnt = (float)(se[1] - se[0]);
        p[t] = pooled_sum[g * F_HID + t] / fmaxf(cnt, 1.0f);
    }
    __syncthreads();
    float acc = bf1[t];
#pragma unroll 8
    for (int k = 0; k < 128; k++) acc = fmaf(p[k], Wf1[k * 256 + t], acc);
    h1[t] = fmaxf(acc, 0.f);
    __syncthreads();
    if (t < 10) {
        float o = bf2[t];
#pragma unroll 8
        for (int j = 0; j < 256; j++) o = fmaf(h1[j], Wf2[j * 10 + t], o);
        out[g * 10 + t] = o;
    }
}

// ---------------- host launch ----------------
extern "C" void kernel_launch(void* const* d_in, const int* in_sizes, int n_in,
                              void* d_out, int out_size, void* d_ws, size_t ws_size,
                              hipStream_t stream) {
    (void)in_sizes; (void)n_in; (void)out_size; (void)ws_size;
    const float* x     = (const float*)d_in[0];
    const int*   ei    = (const int*)d_in[1];
    const int*   batch = (const int*)d_in[2];
    const float* W1    = (const float*)d_in[3];
    const float* g1    = (const float*)d_in[5];
    const float* beta1 = (const float*)d_in[6];
    const float* W2    = (const float*)d_in[7];
    const float* g2    = (const float*)d_in[9];
    const float* beta2 = (const float*)d_in[10];
    const float* W3    = (const float*)d_in[11];
    const float* g3    = (const float*)d_in[13];
    const float* beta3 = (const float*)d_in[14];
    const float* Wf1   = (const float*)d_in[15];
    const float* bf1   = (const float*)d_in[16];
    const float* Wf2   = (const float*)d_in[17];
    const float* bf2   = (const float*)d_in[18];
    float* out = (float*)d_out;

    char* p = (char*)d_ws;
    auto alloc = [&](size_t bytes) { char* q = p; p += (bytes + 255) & ~(size_t)255; return q; };
    // --- zero-init region (one memset): cnt | col | colstats | pooled_sum ---
    char*   zbase     = p;
    int*    cnt       = (int*)   alloc((size_t)N_NODES * 4);
    uint*   col       = (uint*)  alloc((size_t)COL_MAX * 4);           // padded CSR records
    float*  colstats  = (float*) alloc(3 * 256 * 4);
    float*  pooled_sum= (float*) alloc((size_t)N_GRAPHS * F_HID * 4);
    size_t  zbytes    = (size_t)(p - zbase);
    // --- rest ---
    ushort* hbA       = (ushort*)alloc((size_t)N_NODES * F_HID * 2);   // bf16 gemm out
    ushort* hbB       = (ushort*)alloc((size_t)N_NODES * F_HID * 2);   // bf16 agg out
    ushort* W1t       = (ushort*)alloc((size_t)96  * 128 * 2);
    ushort* W2t       = (ushort*)alloc((size_t)128 * 128 * 2);
    ushort* W3t       = (ushort*)alloc((size_t)128 * 128 * 2);
    int*    row_ptr   = (int*)   alloc((size_t)(N_NODES + 1) * 4);
    int*    cursor    = (int*)   alloc((size_t)N_NODES * 4);
    float*  dinv      = (float*) alloc((size_t)N_NODES * 4);
    int*    blockSums = (int*)   alloc(64 * 4);

    // 1. zero accumulators + col (pad records become src=0, w=fp16(0))
    hipMemsetAsync(zbase, 0, zbytes, stream);
    // 2. weight conversions + degree count (merged; x converts in-register inside fillgemm)
    prep_kernel<<<PREP_BLOCKS, 256, 0, stream>>>(ei, W1, W2, W3, W1t, W2t, W3t, cnt);
    // 3-4. scan chain (padded row lengths); finalize re-scans the 49 block sums itself
    scan_blocks_kernel<<<NB_SCAN, 1024, 0, stream>>>(cnt, row_ptr, blockSums);
    finalize_kernel<<<(N_NODES + 255) / 256, 256, 0, stream>>>(row_ptr, blockSums, cnt, dinv, cursor);
    // 5. CSR fill overlapped with layer-1 GEMM (reads f32 x directly)
    fillgemm_kernel<<<GEMM1_BLOCKS + FILL_BLOCKS, 256, 0, stream>>>(ei, dinv, cursor, col, x, W1t, hbA);
    // layer 1: aggregate + stats fused
    aggregate_stats_kernel<<<N_NODES / 16, 1024, 0, stream>>>(hbA, row_ptr, col, hbB, colstats);
    // layer 2
    mfma_gemm_bn_kernel<<<GEMM1_BLOCKS, 256, 0, stream>>>(hbB, colstats, g1, beta1, W2t, hbA);
    aggregate_stats_kernel<<<N_NODES / 16, 1024, 0, stream>>>(hbA, row_ptr, col, hbB, colstats + 256);
    // layer 3
    mfma_gemm_bn_kernel<<<GEMM1_BLOCKS, 256, 0, stream>>>(hbB, colstats + 256, g2, beta2, W3t, hbA);
    aggregate_stats_kernel<<<N_NODES / 16, 1024, 0, stream>>>(hbA, row_ptr, col, hbB, colstats + 512);
    // fused BN+ReLU+pool, then MLP head
    pool_bn_kernel<<<(N_NODES + POOL_ROWS - 1) / POOL_ROWS, 256, 0, stream>>>(hbB, colstats + 512, g3, beta3, batch, pooled_sum);
    mlp_kernel<<<N_GRAPHS, 256, 0, stream>>>(pooled_sum, batch, Wf1, bf1, Wf2, bf2, out);
}

// Round 11
// 442.764 us; speedup vs baseline: 1.2371x; 1.2371x over previous
//
#include <hip/hip_runtime.h>
#include <hip/hip_bf16.h>
#include <hip/hip_fp16.h>

// ---------------- problem constants (match reference) ----------------
constexpr int N_NODES  = 50000;
constexpr int N_EDGES  = 800000;
constexpr int NE_TOT   = N_EDGES + N_NODES;   // edges + self loops
constexpr int COL_MAX  = NE_TOT + 7 * N_NODES; // worst-case padded CSR records
constexpr int F_HID    = 128;
constexpr int N_GRAPHS = 64;
constexpr float BN_EPS = 1e-5f;
constexpr int NB_SCAN  = (N_NODES + 1023) / 1024;   // 49

using short8  = __attribute__((ext_vector_type(8))) short;
using float4v = __attribute__((ext_vector_type(4))) float;

__device__ __forceinline__ ushort f2bf(float f) {
    uint u = __float_as_uint(f);
    return (ushort)((u + 0x7fffu + ((u >> 16) & 1u)) >> 16);   // RNE
}
__device__ __forceinline__ float bflo(uint u) { return __uint_as_float(u << 16); }
__device__ __forceinline__ float bfhi(uint u) { return __uint_as_float(u & 0xffff0000u); }

// ---------------- merged prep: conv_w(all 3) | degree count ----------------
constexpr int CONVW_ELEMS  = 96 * 128 + 2 * 128 * 128;                 // 45056
constexpr int CONVW_BLOCKS = (CONVW_ELEMS + 255) / 256;                // 176
constexpr int COUNT_BLOCKS = (N_EDGES + 255) / 256;                    // 3125
constexpr int PREP_BLOCKS  = CONVW_BLOCKS + COUNT_BLOCKS;

__global__ __launch_bounds__(256) void prep_kernel(const int* __restrict__ ei,
                                                   const float* __restrict__ W1, const float* __restrict__ W2,
                                                   const float* __restrict__ W3,
                                                   ushort* __restrict__ W1t, ushort* __restrict__ W2t,
                                                   ushort* __restrict__ W3t, int* __restrict__ cnt) {
    int b = blockIdx.x;
    if (b < CONVW_BLOCKS) {
        int i = b * 256 + threadIdx.x;
        constexpr int S1 = 96 * 128, S2 = S1 + 128 * 128, S3 = S2 + 128 * 128;
        if (i < S1) {
            int n = i & 127, k = i >> 7;
            W1t[n * 96 + k] = f2bf(W1[i]);
        } else if (i < S2) {
            int j = i - S1, n = j & 127, k = j >> 7;
            W2t[n * 128 + k] = f2bf(W2[j]);
        } else if (i < S3) {
            int j = i - S2, n = j & 127, k = j >> 7;
            W3t[n * 128 + k] = f2bf(W3[j]);
        }
    } else {
        int i = (b - CONVW_BLOCKS) * 256 + threadIdx.x;
        if (i < N_EDGES) atomicAdd(&cnt[ei[N_EDGES + i]], 1);   // dst in-degree (cnt pre-zeroed)
    }
}

// ---------------- scan phase 1: block-local exclusive scan over padded row lengths ----------------
// row length = pad8(cnt[i] + 1)   (+1 self loop, padded to multiple of 8)
__global__ __launch_bounds__(1024) void scan_blocks_kernel(const int* __restrict__ cnt,
                                                           int* __restrict__ row_ptr,
                                                           int* __restrict__ blockSums) {
    int tid = threadIdx.x;
    int gid = blockIdx.x * 1024 + tid;
    int v = (gid < N_NODES) ? ((cnt[gid] + 8) & ~7) : 0;
    int lane = tid & 63, wid = tid >> 6;
    int x = v;
#pragma unroll
    for (int off = 1; off < 64; off <<= 1) {
        int y = __shfl_up(x, off);
        if (lane >= off) x += y;
    }
    __shared__ int wsum[16];
    if (lane == 63) wsum[wid] = x;
    __syncthreads();
    if (tid < 16) {
        int w = wsum[tid];
        int xx = w;
#pragma unroll
        for (int off = 1; off < 16; off <<= 1) {
            int y = __shfl_up(xx, off);
            if (tid >= off) xx += y;
        }
        wsum[tid] = xx - w;
    }
    __syncthreads();
    int incl = x + wsum[wid];
    if (gid < N_NODES) row_ptr[gid] = incl - v;
    if (tid == 1023) blockSums[blockIdx.x] = incl;
}

// ---------------- scan phase 2 (merged totals+finalize): every block re-scans the 49 block sums ----------------
__global__ __launch_bounds__(256) void finalize_kernel(int* __restrict__ row_ptr, const int* __restrict__ blockSums,
                                                       const int* __restrict__ cnt, float* __restrict__ dinv,
                                                       int* __restrict__ cursor) {
    __shared__ int boff[64];
    if (threadIdx.x < 64) {   // one wave: exclusive prefix over blockSums
        int v = (threadIdx.x < NB_SCAN) ? blockSums[threadIdx.x] : 0;
        int x = v;
#pragma unroll
        for (int off = 1; off < 64; off <<= 1) {
            int y = __shfl_up(x, off);
            if ((int)threadIdx.x >= off) x += y;
        }
        boff[threadIdx.x] = x - v;
        if (threadIdx.x == NB_SCAN - 1 && blockIdx.x == 0) row_ptr[N_NODES] = x;   // total
    }
    __syncthreads();
    int i = blockIdx.x * 256 + threadIdx.x;
    if (i >= N_NODES) return;
    int rp = row_ptr[i] + boff[i >> 10];
    row_ptr[i] = rp;
    cursor[i] = rp;
    dinv[i] = rsqrtf((float)(cnt[i] + 1));   // degree incl self loop
}

// ---------------- merged fill | layer-1 MFMA GEMM (f32 A, in-register bf16 convert) ----------------
constexpr int GEMM1_BLOCKS = (N_NODES + 63) / 64;       // 782
constexpr int FILL_BLOCKS  = (NE_TOT + 255) / 256;      // 3321

__global__ __launch_bounds__(256) void fillgemm_kernel(const int* __restrict__ ei, const float* __restrict__ dinv,
                                                       int* __restrict__ cursor, uint* __restrict__ col,
                                                       const float* __restrict__ X, const ushort* __restrict__ Wt,
                                                       ushort* __restrict__ C) {
    if (blockIdx.x < GEMM1_BLOCKS) {
        // ---- layer-1 GEMM: C[N,128] = bf16(X[N,96]) @ W ----
        constexpr int K = 96, KSTEPS = 3;
        int wave = threadIdx.x >> 6, lane = threadIdx.x & 63;
        int m = lane & 15, quad = lane >> 4;
        int row_base = blockIdx.x * 64 + wave * 16;
        short8 afrag[KSTEPS];
        int arow = min(row_base + m, N_NODES - 1);
#pragma unroll
        for (int ks = 0; ks < KSTEPS; ks++) {
            const float* src = X + (size_t)arow * K + ks * 32 + quad * 8;
            float4 a0 = *(const float4*)src;
            float4 a1 = *(const float4*)(src + 4);
            afrag[ks][0] = (short)f2bf(a0.x); afrag[ks][1] = (short)f2bf(a0.y);
            afrag[ks][2] = (short)f2bf(a0.z); afrag[ks][3] = (short)f2bf(a0.w);
            afrag[ks][4] = (short)f2bf(a1.x); afrag[ks][5] = (short)f2bf(a1.y);
            afrag[ks][6] = (short)f2bf(a1.z); afrag[ks][7] = (short)f2bf(a1.w);
        }
#pragma unroll
        for (int nt = 0; nt < 8; nt++) {
            float4v acc = {0.f, 0.f, 0.f, 0.f};
            const ushort* wbase = Wt + (size_t)(nt * 16 + m) * K + quad * 8;
#pragma unroll
            for (int ks = 0; ks < KSTEPS; ks++) {
                short8 bfrag = *(const short8*)(wbase + ks * 32);
                acc = __builtin_amdgcn_mfma_f32_16x16x32_bf16(afrag[ks], bfrag, acc, 0, 0, 0);
            }
            int colg = nt * 16 + m;
#pragma unroll
            for (int r = 0; r < 4; r++) {
                int rowg = row_base + quad * 4 + r;
                if (rowg < N_NODES) C[(size_t)rowg * F_HID + colg] = f2bf(acc[r]);
            }
        }
    } else {
        // ---- CSR fill: packed record (fp16 norm | u16 src), plain 4B scattered store ----
        // (R8: atomicExch cut WRITE 76->65MB but serialized 46->72us. Plain store wins.)
        int i = (blockIdx.x - GEMM1_BLOCKS) * 256 + threadIdx.x;
        if (i >= NE_TOT) return;
        int s, d;
        if (i < N_EDGES) { s = ei[i]; d = ei[N_EDGES + i]; }
        else             { s = i - N_EDGES; d = s; }
        int pos = atomicAdd(&cursor[d], 1);
        float nrm = dinv[s] * dinv[d];
        uint h16 = (uint)__half_as_ushort(__float2half(nrm));
        col[pos] = (h16 << 16) | (uint)s;
    }
}

// ---------------- MFMA transform with fused BN+ReLU on A (layers 2,3), bf16 in/out ----------------
__global__ __launch_bounds__(256) void mfma_gemm_bn_kernel(const ushort* __restrict__ A, const float* __restrict__ cs,
                                                           const float* __restrict__ gam, const float* __restrict__ bet,
                                                           const ushort* __restrict__ Wt, ushort* __restrict__ C) {
    constexpr int K = 128, KSTEPS = 4;
    int wave = threadIdx.x >> 6, lane = threadIdx.x & 63;
    int m = lane & 15, quad = lane >> 4;
    int row_base = blockIdx.x * 64 + wave * 16;
    int arow = min(row_base + m, N_NODES - 1);
    constexpr float invN = 1.0f / N_NODES;

    short8 afrag[KSTEPS];
#pragma unroll
    for (int ks = 0; ks < KSTEPS; ks++) {
        int k0 = ks * 32 + quad * 8;
        uint4 av = *(const uint4*)(A + (size_t)arow * K + k0);   // 8 bf16
        float vals[8] = {bflo(av.x), bfhi(av.x), bflo(av.y), bfhi(av.y),
                         bflo(av.z), bfhi(av.z), bflo(av.w), bfhi(av.w)};
#pragma unroll
        for (int jj = 0; jj < 8; jj += 4) {
            float4 sv = *(const float4*)(cs + k0 + jj);
            float4 qv = *(const float4*)(cs + 128 + k0 + jj);
            float4 gv = *(const float4*)(gam + k0 + jj);
            float4 bv = *(const float4*)(bet + k0 + jj);
            const float* s = (const float*)&sv; const float* q = (const float*)&qv;
            const float* g = (const float*)&gv; const float* b = (const float*)&bv;
#pragma unroll
            for (int t = 0; t < 4; t++) {
                float mean = s[t] * invN;
                float var  = q[t] * invN - mean * mean;
                float sc   = g[t] * rsqrtf(var + BN_EPS);
                float val  = fmaxf((vals[jj + t] - mean) * sc + b[t], 0.0f);
                afrag[ks][jj + t] = (short)f2bf(val);
            }
        }
    }

#pragma unroll
    for (int nt = 0; nt < 8; nt++) {
        float4v acc = {0.f, 0.f, 0.f, 0.f};
        const ushort* wbase = Wt + (size_t)(nt * 16 + m) * K + quad * 8;
#pragma unroll
        for (int ks = 0; ks < KSTEPS; ks++) {
            short8 bfrag = *(const short8*)(wbase + ks * 32);
            acc = __builtin_amdgcn_mfma_f32_16x16x32_bf16(afrag[ks], bfrag, acc, 0, 0, 0);
        }
        int colg = nt * 16 + m;
#pragma unroll
        for (int r = 0; r < 4; r++) {
            int rowg = row_base + quad * 4 + r;
            if (rowg < N_NODES) C[(size_t)rowg * F_HID + colg] = f2bf(acc[r]);
        }
    }
}

// ---------------- sparse aggregation: one wave per dst row, quarter-wave gathers ----------------
// (R10 fused stats into this with 1024-thread blocks: the __syncthreads load-imbalance
//  barrier + LDS-atomic tail took it 35->95us. Keep waves independent; stats separate.)
__global__ __launch_bounds__(256) void aggregate_kernel(const ushort* __restrict__ h, const int* __restrict__ row_ptr,
                                                        const uint* __restrict__ col, ushort* __restrict__ outp) {
    int wv   = (blockIdx.x * 256 + threadIdx.x) >> 6;
    int lane = threadIdx.x & 63;
    if (wv >= N_NODES) return;
    int q  = lane >> 4;     // 0..3 edge slot
    int sl = lane & 15;     // col group
    int beg = row_ptr[wv], end = row_ptr[wv + 1];
    float a0 = 0, a1 = 0, a2 = 0, a3 = 0, a4 = 0, a5 = 0, a6 = 0, a7 = 0;
    int base = beg;
    for (; base + 16 <= end; base += 16) {   // 16 edges per iteration, 4 gathers in flight per lane
        uint r0 = col[base + q];
        uint r1 = col[base + 4 + q];
        uint r2 = col[base + 8 + q];
        uint r3 = col[base + 12 + q];
        uint4 v0 = *(const uint4*)(h + (size_t)(r0 & 0xFFFFu) * F_HID + sl * 8);
        uint4 v1 = *(const uint4*)(h + (size_t)(r1 & 0xFFFFu) * F_HID + sl * 8);
        uint4 v2 = *(const uint4*)(h + (size_t)(r2 & 0xFFFFu) * F_HID + sl * 8);
        uint4 v3 = *(const uint4*)(h + (size_t)(r3 & 0xFFFFu) * F_HID + sl * 8);
        float w0 = __half2float(__ushort_as_half((ushort)(r0 >> 16)));
        float w1 = __half2float(__ushort_as_half((ushort)(r1 >> 16)));
        float w2 = __half2float(__ushort_as_half((ushort)(r2 >> 16)));
        float w3 = __half2float(__ushort_as_half((ushort)(r3 >> 16)));
        a0 += w0 * bflo(v0.x); a1 += w0 * bfhi(v0.x); a2 += w0 * bflo(v0.y); a3 += w0 * bfhi(v0.y);
        a4 += w0 * bflo(v0.z); a5 += w0 * bfhi(v0.z); a6 += w0 * bflo(v0.w); a7 += w0 * bfhi(v0.w);
        a0 += w1 * bflo(v1.x); a1 += w1 * bfhi(v1.x); a2 += w1 * bflo(v1.y); a3 += w1 * bfhi(v1.y);
        a4 += w1 * bflo(v1.z); a5 += w1 * bfhi(v1.z); a6 += w1 * bflo(v1.w); a7 += w1 * bfhi(v1.w);
        a0 += w2 * bflo(v2.x); a1 += w2 * bfhi(v2.x); a2 += w2 * bflo(v2.y); a3 += w2 * bfhi(v2.y);
        a4 += w2 * bflo(v2.z); a5 += w2 * bfhi(v2.z); a6 += w2 * bflo(v2.w); a7 += w2 * bfhi(v2.w);
        a0 += w3 * bflo(v3.x); a1 += w3 * bfhi(v3.x); a2 += w3 * bflo(v3.y); a3 += w3 * bfhi(v3.y);
        a4 += w3 * bflo(v3.z); a5 += w3 * bfhi(v3.z); a6 += w3 * bflo(v3.w); a7 += w3 * bfhi(v3.w);
    }
    if (base < end) {   // exactly 8 remain (row length % 8 == 0)
        uint r0 = col[base + q];
        uint r1 = col[base + 4 + q];
        uint4 v0 = *(const uint4*)(h + (size_t)(r0 & 0xFFFFu) * F_HID + sl * 8);
        uint4 v1 = *(const uint4*)(h + (size_t)(r1 & 0xFFFFu) * F_HID + sl * 8);
        float w0 = __half2float(__ushort_as_half((ushort)(r0 >> 16)));
        float w1 = __half2float(__ushort_as_half((ushort)(r1 >> 16)));
        a0 += w0 * bflo(v0.x); a1 += w0 * bfhi(v0.x); a2 += w0 * bflo(v0.y); a3 += w0 * bfhi(v0.y);
        a4 += w0 * bflo(v0.z); a5 += w0 * bfhi(v0.z); a6 += w0 * bflo(v0.w); a7 += w0 * bfhi(v0.w);
        a0 += w1 * bflo(v1.x); a1 += w1 * bfhi(v1.x); a2 += w1 * bflo(v1.y); a3 += w1 * bfhi(v1.y);
        a4 += w1 * bflo(v1.z); a5 += w1 * bfhi(v1.z); a6 += w1 * bflo(v1.w); a7 += w1 * bfhi(v1.w);
    }
    // combine quarters: +16 then +32
    a0 += __shfl_down(a0, 16); a1 += __shfl_down(a1, 16); a2 += __shfl_down(a2, 16); a3 += __shfl_down(a3, 16);
    a4 += __shfl_down(a4, 16); a5 += __shfl_down(a5, 16); a6 += __shfl_down(a6, 16); a7 += __shfl_down(a7, 16);
    a0 += __shfl_down(a0, 32); a1 += __shfl_down(a1, 32); a2 += __shfl_down(a2, 32); a3 += __shfl_down(a3, 32);
    a4 += __shfl_down(a4, 32); a5 += __shfl_down(a5, 32); a6 += __shfl_down(a6, 32); a7 += __shfl_down(a7, 32);
    if (q == 0) {
        uint4 o;
        o.x = (uint)f2bf(a0) | ((uint)f2bf(a1) << 16);
        o.y = (uint)f2bf(a2) | ((uint)f2bf(a3) << 16);
        o.z = (uint)f2bf(a4) | ((uint)f2bf(a5) << 16);
        o.w = (uint)f2bf(a6) | ((uint)f2bf(a7) << 16);
        *(uint4*)(outp + (size_t)wv * F_HID + sl * 8) = o;
    }
}

// ---------------- BN stats (column sums / sumsq over bf16 agg) ----------------
__global__ __launch_bounds__(256) void stats_kernel(const ushort* __restrict__ h, float* __restrict__ colstats) {
    int c4 = (threadIdx.x & 31) * 4;
    int stripe = threadIdx.x >> 5;   // 0..7
    float s0 = 0, s1 = 0, s2 = 0, s3 = 0, q0 = 0, q1 = 0, q2 = 0, q3 = 0;
    for (int n = blockIdx.x * 8 + stripe; n < N_NODES; n += gridDim.x * 8) {
        uint2 v = *(const uint2*)(h + (size_t)n * F_HID + c4);
        float x0 = bflo(v.x), x1 = bfhi(v.x), x2 = bflo(v.y), x3 = bfhi(v.y);
        s0 += x0; s1 += x1; s2 += x2; s3 += x3;
        q0 += x0 * x0; q1 += x1 * x1; q2 += x2 * x2; q3 += x3 * x3;
    }
    __shared__ float sh[8][256];
    sh[0][threadIdx.x] = s0; sh[1][threadIdx.x] = s1; sh[2][threadIdx.x] = s2; sh[3][threadIdx.x] = s3;
    sh[4][threadIdx.x] = q0; sh[5][threadIdx.x] = q1; sh[6][threadIdx.x] = q2; sh[7][threadIdx.x] = q3;
    __syncthreads();
    if (stripe == 0) {
        int t = threadIdx.x;
#pragma unroll
        for (int c = 0; c < 4; c++) {
            float ts = 0, tq = 0;
#pragma unroll
            for (int k = 0; k < 8; k++) { ts += sh[c][k * 32 + t]; tq += sh[4 + c][k * 32 + t]; }
            atomicAdd(&colstats[c4 + c],       ts);
            atomicAdd(&colstats[128 + c4 + c], tq);
        }
    }
}

// ---------------- fused layer-3 BN+ReLU + graph pooling (bf16 in) ----------------
constexpr int POOL_ROWS = 128;
__global__ __launch_bounds__(256) void pool_bn_kernel(const ushort* __restrict__ h, const float* __restrict__ cs,
                                                      const float* __restrict__ gam, const float* __restrict__ bet,
                                                      const int* __restrict__ batch, float* __restrict__ pooled_sum) {
    int row0 = blockIdx.x * POOL_ROWS;
    int c4 = (threadIdx.x & 31) * 4;
    int stripe = threadIdx.x >> 5;   // 0..7
    __shared__ int sbatch[POOL_ROWS];
    if (threadIdx.x < POOL_ROWS) {
        int r = row0 + threadIdx.x;
        sbatch[threadIdx.x] = (r < N_NODES) ? batch[r] : -1;
    }
    __syncthreads();
    int nrows = min(POOL_ROWS, N_NODES - row0);
    if (stripe >= nrows) return;
    constexpr float invN = 1.0f / N_NODES;
    float mean[4], scl[4], bb[4];
#pragma unroll
    for (int t = 0; t < 4; t++) {
        float mn = cs[c4 + t] * invN;
        float var = cs[128 + c4 + t] * invN - mn * mn;
        mean[t] = mn;
        scl[t] = gam[c4 + t] * rsqrtf(var + BN_EPS);
        bb[t] = bet[c4 + t];
    }
    int cur = sbatch[stripe];
    float a0 = 0, a1 = 0, a2 = 0, a3 = 0;
    for (int r = stripe; r < nrows; r += 8) {
        int g = sbatch[r];
        if (g != cur) {
            atomicAdd(&pooled_sum[cur * F_HID + c4 + 0], a0);
            atomicAdd(&pooled_sum[cur * F_HID + c4 + 1], a1);
            atomicAdd(&pooled_sum[cur * F_HID + c4 + 2], a2);
            atomicAdd(&pooled_sum[cur * F_HID + c4 + 3], a3);
            cur = g; a0 = a1 = a2 = a3 = 0.f;
        }
        uint2 v = *(const uint2*)(h + (size_t)(row0 + r) * F_HID + c4);
        a0 += fmaxf((bflo(v.x) - mean[0]) * scl[0] + bb[0], 0.f);
        a1 += fmaxf((bfhi(v.x) - mean[1]) * scl[1] + bb[1], 0.f);
        a2 += fmaxf((bflo(v.y) - mean[2]) * scl[2] + bb[2], 0.f);
        a3 += fmaxf((bfhi(v.y) - mean[3]) * scl[3] + bb[3], 0.f);
    }
    atomicAdd(&pooled_sum[cur * F_HID + c4 + 0], a0);
    atomicAdd(&pooled_sum[cur * F_HID + c4 + 1], a1);
    atomicAdd(&pooled_sum[cur * F_HID + c4 + 2], a2);
    atomicAdd(&pooled_sum[cur * F_HID + c4 + 3], a3);
}

// ---------------- MLP head (boundary search + divide-by-count folded in) ----------------
__global__ __launch_bounds__(256) void mlp_kernel(const float* __restrict__ pooled_sum, const int* __restrict__ batch,
                                                  const float* __restrict__ Wf1, const float* __restrict__ bf1,
                                                  const float* __restrict__ Wf2, const float* __restrict__ bf2,
                                                  float* __restrict__ out) {
    __shared__ float p[128];
    __shared__ float h1[256];
    __shared__ int se[2];
    int g = blockIdx.x, t = threadIdx.x;
    if (t < 2) {   // lower_bound(batch, g + t)
        int target = g + t;
        int lo = 0, hi = N_NODES;
        while (lo < hi) {
            int mid = (lo + hi) >> 1;
            if (batch[mid] < target) lo = mid + 1; else hi = mid;
        }
        se[t] = lo;
    }
    __syncthreads();
    if (t < 128) {
        float cnt = (float)(se[1] - se[0]);
        p[t] = pooled_sum[g * F_HID + t] / fmaxf(cnt, 1.0f);
    }
    __syncthreads();
    float acc = bf1[t];
#pragma unroll 8
    for (int k = 0; k < 128; k++) acc = fmaf(p[k], Wf1[k * 256 + t], acc);
    h1[t] = fmaxf(acc, 0.f);
    __syncthreads();
    if (t < 10) {
        float o = bf2[t];
#pragma unroll 8
        for (int j = 0; j < 256; j++) o = fmaf(h1[j], Wf2[j * 10 + t], o);
        out[g * 10 + t] = o;
    }
}

// ---------------- host launch ----------------
extern "C" void kernel_launch(void* const* d_in, const int* in_sizes, int n_in,
                              void* d_out, int out_size, void* d_ws, size_t ws_size,
                              hipStream_t stream) {
    (void)in_sizes; (void)n_in; (void)out_size; (void)ws_size;
    const float* x     = (const float*)d_in[0];
    const int*   ei    = (const int*)d_in[1];
    const int*   batch = (const int*)d_in[2];
    const float* W1    = (const float*)d_in[3];
    const float* g1    = (const float*)d_in[5];
    const float* beta1 = (const float*)d_in[6];
    const float* W2    = (const float*)d_in[7];
    const float* g2    = (const float*)d_in[9];
    const float* beta2 = (const float*)d_in[10];
    const float* W3    = (const float*)d_in[11];
    const float* g3    = (const float*)d_in[13];
    const float* beta3 = (const float*)d_in[14];
    const float* Wf1   = (const float*)d_in[15];
    const float* bf1   = (const float*)d_in[16];
    const float* Wf2   = (const float*)d_in[17];
    const float* bf2   = (const float*)d_in[18];
    float* out = (float*)d_out;

    char* p = (char*)d_ws;
    auto alloc = [&](size_t bytes) { char* q = p; p += (bytes + 255) & ~(size_t)255; return q; };
    // --- zero-init region (one memset): cnt | col | colstats | pooled_sum ---
    char*   zbase     = p;
    int*    cnt       = (int*)   alloc((size_t)N_NODES * 4);
    uint*   col       = (uint*)  alloc((size_t)COL_MAX * 4);           // padded CSR records
    float*  colstats  = (float*) alloc(3 * 256 * 4);
    float*  pooled_sum= (float*) alloc((size_t)N_GRAPHS * F_HID * 4);
    size_t  zbytes    = (size_t)(p - zbase);
    // --- rest ---
    ushort* hbA       = (ushort*)alloc((size_t)N_NODES * F_HID * 2);   // bf16 gemm out
    ushort* hbB       = (ushort*)alloc((size_t)N_NODES * F_HID * 2);   // bf16 agg out
    ushort* W1t       = (ushort*)alloc((size_t)96  * 128 * 2);
    ushort* W2t       = (ushort*)alloc((size_t)128 * 128 * 2);
    ushort* W3t       = (ushort*)alloc((size_t)128 * 128 * 2);
    int*    row_ptr   = (int*)   alloc((size_t)(N_NODES + 1) * 4);
    int*    cursor    = (int*)   alloc((size_t)N_NODES * 4);
    float*  dinv      = (float*) alloc((size_t)N_NODES * 4);
    int*    blockSums = (int*)   alloc(64 * 4);

    // 1. zero accumulators + col (pad records become src=0, w=fp16(0))
    hipMemsetAsync(zbase, 0, zbytes, stream);
    // 2. weight conversions + degree count (merged; x converts in-register inside fillgemm)
    prep_kernel<<<PREP_BLOCKS, 256, 0, stream>>>(ei, W1, W2, W3, W1t, W2t, W3t, cnt);
    // 3-4. scan chain (padded row lengths); finalize re-scans the 49 block sums itself
    scan_blocks_kernel<<<NB_SCAN, 1024, 0, stream>>>(cnt, row_ptr, blockSums);
    finalize_kernel<<<(N_NODES + 255) / 256, 256, 0, stream>>>(row_ptr, blockSums, cnt, dinv, cursor);
    // 5. CSR fill overlapped with layer-1 GEMM (reads f32 x directly)
    fillgemm_kernel<<<GEMM1_BLOCKS + FILL_BLOCKS, 256, 0, stream>>>(ei, dinv, cursor, col, x, W1t, hbA);
    // layer 1
    aggregate_kernel<<<N_NODES / 4, 256, 0, stream>>>(hbA, row_ptr, col, hbB);
    stats_kernel<<<256, 256, 0, stream>>>(hbB, colstats);
    // layer 2
    mfma_gemm_bn_kernel<<<GEMM1_BLOCKS, 256, 0, stream>>>(hbB, colstats, g1, beta1, W2t, hbA);
    aggregate_kernel<<<N_NODES / 4, 256, 0, stream>>>(hbA, row_ptr, col, hbB);
    stats_kernel<<<256, 256, 0, stream>>>(hbB, colstats + 256);
    // layer 3
    mfma_gemm_bn_kernel<<<GEMM1_BLOCKS, 256, 0, stream>>>(hbB, colstats + 256, g2, beta2, W3t, hbA);
    aggregate_kernel<<<N_NODES / 4, 256, 0, stream>>>(hbA, row_ptr, col, hbB);
    stats_kernel<<<256, 256, 0, stream>>>(hbB, colstats + 512);
    // fused BN+ReLU+pool, then MLP head
    pool_bn_kernel<<<(N_NODES + POOL_ROWS - 1) / POOL_ROWS, 256, 0, stream>>>(hbB, colstats + 512, g3, beta3, batch, pooled_sum);
    mlp_kernel<<<N_GRAPHS, 256, 0, stream>>>(pooled_sum, batch, Wf1, bf1, Wf2, bf2, out);
}